// Round 1
// baseline (1834.126 us; speedup 1.0000x reference)
//
#include <hip/hip_runtime.h>

#define NN 50000
#define EE 800000
#define FIN 128
#define DD 64
#define RR 8
#define LL 3

#define ND (NN*DD)      // 3,200,000
#define NR (NN*RR)      // 400,000

#define SB 1024
#define NSB ((NR + SB - 1) / SB)   // 391
#define ECAP 2048
#define AS 72           // LDS A-tile row stride in shorts (bank-spread)
#define KB 576          // K total per layer GEMM (8 rel + root) * 64

typedef __attribute__((ext_vector_type(8))) short bf16x8;
typedef __attribute__((ext_vector_type(4))) float f32x4;

__device__ __forceinline__ unsigned short f2bf(float x) {
  unsigned u = __float_as_uint(x);
  u += 0x7fff + ((u >> 16) & 1);           // round-to-nearest-even
  return (unsigned short)(u >> 16);
}
__device__ __forceinline__ void split_bf(float x, short& h, short& l) {
  unsigned short hu = f2bf(x);
  float hf = __uint_as_float((unsigned)hu << 16);
  h = (short)hu;
  l = (short)f2bf(x - hf);
}

// ---- precompute bf16 hi/lo transposed weights -------------------------------
// Btp[l][p][n][k] (k: 8*64 rel + 64 root), flat ((l*2+p)*64+n)*KB + k
__global__ void k_prepB(const float* __restrict__ W_rel,
                        const float* __restrict__ W_root,
                        short* __restrict__ Btp) {
  const int idx = blockIdx.x * 256 + threadIdx.x;
  if (idx >= LL * DD * KB) return;
  const int k = idx % KB, n = (idx / KB) % DD, l = idx / (KB * DD);
  float w;
  if (k < 512) w = W_rel[(((size_t)l*RR + (k >> 6))*DD + (k & 63))*DD + n];
  else         w = W_root[((size_t)l*DD + (k - 512))*DD + n];
  short hi, lo; split_bf(w, hi, lo);
  Btp[((size_t)(l*2+0)*DD + n)*KB + k] = hi;
  Btp[((size_t)(l*2+1)*DD + n)*KB + k] = lo;
}
// Wt[p][n][k], flat (p*64+n)*128+k
__global__ void k_prepWin(const float* __restrict__ W_in, short* __restrict__ Wt) {
  const int idx = blockIdx.x * 256 + threadIdx.x;
  if (idx >= 2 * DD * FIN) return;
  if (idx >= DD * FIN) return;
  const int k = idx % FIN, n = idx / FIN;
  float w = W_in[(size_t)k*DD + n];
  short hi, lo; split_bf(w, hi, lo);
  Wt[((size_t)0*DD + n)*FIN + k] = hi;
  Wt[((size_t)1*DD + n)*FIN + k] = lo;
}

// ---- input projection: h = relu(x @ W_in + b_in) via split-bf16 MFMA --------
__global__ __launch_bounds__(256) void k_input_mfma(
    const float* __restrict__ x, const short* __restrict__ Wt,
    const float* __restrict__ b, float* __restrict__ h) {
  __shared__ short Ah[DD * 136];   // 64 rows x K=128, stride 136
  __shared__ short Al[DD * 136];
  const int t = threadIdx.x;
  const int lane = t & 63, wv = t >> 6;
  const int lr = lane & 15, lc = lane >> 4;
  const int n0 = blockIdx.x * 64;

  { // stage x rows as hi/lo bf16
    const int row = t >> 2, cb = (t & 3) * 32;
    const int n = n0 + row;
    #pragma unroll
    for (int i = 0; i < 8; ++i) {
      const int col = cb + i * 4;
      float4 v = make_float4(0.f,0.f,0.f,0.f);
      if (n < NN) v = *(const float4*)(x + (size_t)n*FIN + col);
      short h0,l0,h1,l1,h2,l2,h3,l3;
      split_bf(v.x,h0,l0); split_bf(v.y,h1,l1);
      split_bf(v.z,h2,l2); split_bf(v.w,h3,l3);
      unsigned long long ph = (unsigned short)h0 | ((unsigned long long)(unsigned short)h1<<16)
          | ((unsigned long long)(unsigned short)h2<<32) | ((unsigned long long)(unsigned short)h3<<48);
      unsigned long long pl = (unsigned short)l0 | ((unsigned long long)(unsigned short)l1<<16)
          | ((unsigned long long)(unsigned short)l2<<32) | ((unsigned long long)(unsigned short)l3<<48);
      *(unsigned long long*)&Ah[row*136 + col] = ph;
      *(unsigned long long*)&Al[row*136 + col] = pl;
    }
  }
  __syncthreads();

  const int m0 = wv * 16;
  f32x4 acc[4];
  #pragma unroll
  for (int nt = 0; nt < 4; ++nt) acc[nt] = (f32x4){0.f,0.f,0.f,0.f};
  const int aoff = (m0 + lr)*136 + lc*8;
  int boff[4];
  #pragma unroll
  for (int nt = 0; nt < 4; ++nt) boff[nt] = (nt*16 + lr)*FIN + lc*8;

  #pragma unroll
  for (int ks = 0; ks < 4; ++ks) {
    const bf16x8 ah = *(const bf16x8*)&Ah[aoff + ks*32];
    const bf16x8 al = *(const bf16x8*)&Al[aoff + ks*32];
    #pragma unroll
    for (int nt = 0; nt < 4; ++nt) {
      const bf16x8 bh = *(const bf16x8*)(Wt + boff[nt] + ks*32);
      const bf16x8 bl = *(const bf16x8*)(Wt + DD*FIN + boff[nt] + ks*32);
      acc[nt] = __builtin_amdgcn_mfma_f32_16x16x32_bf16(ah, bh, acc[nt], 0, 0, 0);
      acc[nt] = __builtin_amdgcn_mfma_f32_16x16x32_bf16(al, bh, acc[nt], 0, 0, 0);
      acc[nt] = __builtin_amdgcn_mfma_f32_16x16x32_bf16(ah, bl, acc[nt], 0, 0, 0);
    }
  }
  #pragma unroll
  for (int nt = 0; nt < 4; ++nt) {
    const float bb = b[nt*16 + lr];
    #pragma unroll
    for (int i = 0; i < 4; ++i) {
      const int m = n0 + m0 + lc*4 + i;
      if (m < NN) h[(size_t)m*DD + nt*16 + lr] = fmaxf(acc[nt][i] + bb, 0.f);
    }
  }
}

// ---------------- CSR build keyed by (et * NN + dst) ------------------------
__global__ void k_hist(const int* __restrict__ ei, const float* __restrict__ ea,
                       int* __restrict__ rp) {
  const int e = blockIdx.x * 256 + threadIdx.x;
  if (e >= EE) return;
  atomicAdd(&rp[(int)ea[2*e + 1] * NN + ei[EE + e]], 1);
}

__global__ __launch_bounds__(256) void k_scan1(int* __restrict__ rp,
                                               int* __restrict__ part) {
  __shared__ int ls[256];
  const int t = threadIdx.x;
  const int base = blockIdx.x * SB + t * 4;
  int v[4] = {0,0,0,0};
  #pragma unroll
  for (int i = 0; i < 4; ++i)
    if (base + i < NR) v[i] = rp[base + i];
  const int tsum = v[0] + v[1] + v[2] + v[3];
  ls[t] = tsum; __syncthreads();
  #pragma unroll
  for (int off = 1; off < 256; off <<= 1) {
    int x = (t >= off) ? ls[t - off] : 0;
    __syncthreads();
    ls[t] += x;
    __syncthreads();
  }
  if (t == 255) part[blockIdx.x] = ls[255];
  int run = ls[t] - tsum;
  #pragma unroll
  for (int i = 0; i < 4; ++i) {
    if (base + i < NR) rp[base + i] = run;
    run += v[i];
  }
}

__global__ __launch_bounds__(512) void k_scan2(int* __restrict__ part) {
  __shared__ int ls[512];
  const int t = threadIdx.x;
  const int v = (t < NSB) ? part[t] : 0;
  ls[t] = v; __syncthreads();
  #pragma unroll
  for (int off = 1; off < 512; off <<= 1) {
    int x = (t >= off) ? ls[t - off] : 0;
    __syncthreads();
    ls[t] += x;
    __syncthreads();
  }
  if (t < NSB) part[t] = ls[t] - v;
}

__global__ __launch_bounds__(256) void k_scan3(int* __restrict__ rp,
                                               const int* __restrict__ part,
                                               int* __restrict__ fill) {
  const int base = blockIdx.x * SB + threadIdx.x * 4;
  const int off = part[blockIdx.x];
  #pragma unroll
  for (int i = 0; i < 4; ++i)
    if (base + i < NR) {
      const int r = rp[base + i] + off;
      rp[base + i] = r;
      fill[base + i] = r;
    }
  if (blockIdx.x == 0 && threadIdx.x == 0) rp[NR] = EE;
}

__global__ void k_reorder(const int* __restrict__ ei, const float* __restrict__ ea,
                          int* __restrict__ fill, unsigned short* __restrict__ eidx) {
  const int e = blockIdx.x * 256 + threadIdx.x;
  if (e >= EE) return;
  const int key = (int)ea[2*e + 1] * NN + ei[EE + e];
  const int pos = atomicAdd(&fill[key], 1);
  eidx[pos] = (unsigned short)ei[e];
}

// ---------------- fused per-layer kernel -------------------------------------
// 64 dst nodes / block, 256 threads. Per relation: edge-interleaved gather
// across all 4 waves into an LDS f32 accumulator tile (ds_add_f32), 16-deep
// two-stage pipelined h-row loads; then a convert phase (mean -> split-bf16)
// feeds the MFMA K-slice. MFMA(kk) overlaps gather(kk+1) loads (no barrier
// between them).
__global__ __launch_bounds__(256) void k_layer(
    const float* __restrict__ h, const unsigned short* __restrict__ eidx,
    const int* __restrict__ rp, const short* __restrict__ Btp,
    const float* __restrict__ bias, float* __restrict__ outh) {
  __shared__ float Aacc[DD * DD];          // 16,384 B
  __shared__ short Ah[DD * AS];            //  9,216 B
  __shared__ short Al[DD * AS];            //  9,216 B
  __shared__ unsigned short els[ECAP];     //  4,096 B
  __shared__ int rpls[RR][65];             //  2,080 B
  __shared__ int baseL[RR + 1];

  const int t = threadIdx.x;
  const int lane = t & 63, wv = t >> 6;
  const int lr = lane & 15, lc = lane >> 4;
  const int n0 = blockIdx.x * 64;
  const float* hl = h + lane;

  for (int i = t; i < RR * 65; i += 256) {
    const int kk = i / 65, j = i - kk * 65;
    int g = n0 + j; if (g > NN) g = NN;
    rpls[kk][j] = rp[kk * NN + g];
  }
  #pragma unroll
  for (int i = 0; i < (DD*DD)/256; ++i) Aacc[i*256 + t] = 0.f;
  __syncthreads();
  if (t == 0) {
    int s = 0;
    #pragma unroll
    for (int k = 0; k < RR; ++k) { baseL[k] = s; s += rpls[k][64] - rpls[k][0]; }
    baseL[RR] = s;
  }
  __syncthreads();
  const bool fit = baseL[RR] <= ECAP;
  if (fit) {
    for (int k = 0; k < RR; ++k) {
      const int g0 = rpls[k][0], sp = rpls[k][64] - g0, b0 = baseL[k];
      for (int i = t; i < sp; i += 256) els[b0 + i] = eidx[g0 + i];
    }
  }
  __syncthreads();

  const int m0 = wv * 16;
  f32x4 acc[4];
  #pragma unroll
  for (int nt = 0; nt < 4; ++nt) acc[nt] = (f32x4){0.f,0.f,0.f,0.f};
  const int aoff = (m0 + lr) * AS + lc * 8;
  int boff[4];
  #pragma unroll
  for (int nt = 0; nt < 4; ++nt) boff[nt] = (nt*16 + lr)*KB + lc*8;
  const short* Blo = Btp + (size_t)DD * KB;
  const int jbase = wv * 16;               // convert-phase row block

  #pragma unroll 1
  for (int kk = 0; kk < 9; ++kk) {
    if (kk < 8) {
      // ---- gather: edges of this rel interleaved across the 4 waves ----
      const int ebeg = rpls[kk][0], eend = rpls[kk][64];
      const int lb2 = baseL[kk] - ebeg;
      int j = 0, nxt = rpls[kk][1];
      float va[16], vb[16];
      auto issue = [&](float (&buf)[16], int base) {
        #pragma unroll
        for (int i = 0; i < 16; ++i) {
          const int ee = base + i*4;
          int s = 0;
          if (ee < eend) s = fit ? (int)els[lb2 + ee] : (int)eidx[ee];
          buf[i] = hl[(size_t)s * DD];
        }
      };
      auto proc = [&](float (&buf)[16], int base) {
        #pragma unroll
        for (int i = 0; i < 16; ++i) {
          const int ee = base + i*4;
          if (ee < eend) {
            while (ee >= nxt) { ++j; nxt = rpls[kk][j + 1]; }
            atomicAdd(&Aacc[j * DD + lane], buf[i]);
          }
        }
      };
      int e = ebeg + wv;
      if (e < eend) {
        issue(va, e);
        while (true) {
          int en = e + 64;
          if (en >= eend) { proc(va, e); break; }
          issue(vb, en);
          proc(va, e);
          e = en; en = e + 64;
          if (en >= eend) { proc(vb, e); break; }
          issue(va, en);
          proc(vb, e);
          e = en;
        }
      }
    }
    __syncthreads();   // B1: atomics done; previous MFMA done before Ah/Al rewrite
    if (kk < 8) {
      // ---- convert: mean + split-bf16, zero acc for next rel ----
      #pragma unroll
      for (int jj = 0; jj < 16; ++jj) {
        const int jg = jbase + jj;
        const float a = Aacc[jg * DD + lane];
        const int cnt = rpls[kk][jg + 1] - rpls[kk][jg];
        const float m = (cnt > 1) ? a * (1.0f / (float)cnt) : a;
        short hb, lb; split_bf(m, hb, lb);
        Ah[jg * AS + lane] = hb;
        Al[jg * AS + lane] = lb;
        Aacc[jg * DD + lane] = 0.f;
      }
    } else {
      // ---- root: stage h rows directly ----
      #pragma unroll
      for (int jj = 0; jj < 16; ++jj) {
        const int n = n0 + jbase + jj;
        const float v = (n < NN) ? h[(size_t)n * DD + lane] : 0.f;
        short hb, lb; split_bf(v, hb, lb);
        Ah[(jbase + jj) * AS + lane] = hb;
        Al[(jbase + jj) * AS + lane] = lb;
      }
    }
    __syncthreads();   // B2: Ah/Al + zeroed acc visible
    // ---- MFMA: C += A_kk @ B_kk (overlaps next iter's gather loads) ----
    const int koff = kk * 64;
    #pragma unroll
    for (int ks = 0; ks < 2; ++ks) {
      const bf16x8 ah = *(const bf16x8*)&Ah[aoff + ks*32];
      const bf16x8 al = *(const bf16x8*)&Al[aoff + ks*32];
      #pragma unroll
      for (int nt = 0; nt < 4; ++nt) {
        const bf16x8 bh = *(const bf16x8*)(Btp + boff[nt] + koff + ks*32);
        const bf16x8 bl = *(const bf16x8*)(Blo + boff[nt] + koff + ks*32);
        acc[nt] = __builtin_amdgcn_mfma_f32_16x16x32_bf16(ah, bh, acc[nt], 0, 0, 0);
        acc[nt] = __builtin_amdgcn_mfma_f32_16x16x32_bf16(al, bh, acc[nt], 0, 0, 0);
        acc[nt] = __builtin_amdgcn_mfma_f32_16x16x32_bf16(ah, bl, acc[nt], 0, 0, 0);
      }
    }
  }

  #pragma unroll
  for (int nt = 0; nt < 4; ++nt) {
    const float bb = bias[nt*16 + lr];
    #pragma unroll
    for (int i = 0; i < 4; ++i) {
      const int m = n0 + m0 + lc*4 + i;
      if (m < NN) outh[(size_t)m*DD + nt*16 + lr] = fmaxf(acc[nt][i] + bb, 0.f);
    }
  }
}

__global__ void k_edist(const float* __restrict__ ea, float* __restrict__ out) {
  const int e = blockIdx.x * 256 + threadIdx.x;
  if (e < EE) out[e] = ea[2*e];
}

extern "C" void kernel_launch(void* const* d_in, const int* in_sizes, int n_in,
                              void* d_out, int out_size, void* d_ws, size_t ws_size,
                              hipStream_t stream) {
  const float* x      = (const float*)d_in[0];
  const int*   ei     = (const int*)d_in[1];
  const float* ea     = (const float*)d_in[2];
  const float* W_in   = (const float*)d_in[3];
  const float* b_in   = (const float*)d_in[4];
  const float* W_rel  = (const float*)d_in[5];
  const float* W_root = (const float*)d_in[6];
  const float* b_conv = (const float*)d_in[7];
  float* out = (float*)d_out;

  // ws layout (~30.9 MB)
  char* ws = (char*)d_ws;
  float*          hA   = (float*)(ws);                       // 12,800,000
  float*          hB   = (float*)(ws + 12800000);            // 12,800,000
  int*            rp   = (int*)  (ws + 25600000);            // 1,600,256
  int*            fill = (int*)  (ws + 27200256);            // 1,600,000
  unsigned short* eidx = (unsigned short*)(ws + 28800256);   // 1,600,000
  int*            part = (int*)  (ws + 30400256);            // 2,048
  short*          Btp  = (short*)(ws + 30402304);            // 442,368
  short*          Wt   = (short*)(ws + 30844672);            // 32,768

  k_edist<<<(EE + 255)/256, 256, 0, stream>>>(ea, out + (size_t)ND);
  k_prepB<<<(LL*DD*KB + 255)/256, 256, 0, stream>>>(W_rel, W_root, Btp);
  k_prepWin<<<(DD*FIN + 255)/256, 256, 0, stream>>>(W_in, Wt);
  k_input_mfma<<<(NN + 63)/64, 256, 0, stream>>>(x, Wt, b_in, hA);

  // CSR keyed (et, dst) — built once, reused by all 3 layers
  hipMemsetAsync(rp, 0, (size_t)NR*4, stream);
  k_hist<<<(EE + 255)/256, 256, 0, stream>>>(ei, ea, rp);
  k_scan1<<<NSB, 256, 0, stream>>>(rp, part);
  k_scan2<<<1, 512, 0, stream>>>(part);
  k_scan3<<<NSB, 256, 0, stream>>>(rp, part, fill);
  k_reorder<<<(EE + 255)/256, 256, 0, stream>>>(ei, ea, fill, eidx);

  const int NBL = (NN + 63) / 64;   // 782
  const float* hin = hA;
  for (int l = 0; l < LL; ++l) {
    float* hout = (l == 2) ? out : ((l == 0) ? hB : hA);
    k_layer<<<NBL, 256, 0, stream>>>(hin, eidx, rp,
        Btp + (size_t)l*2*DD*KB, b_conv + (size_t)l*DD, hout);
    hin = hout;
  }
}

// Round 2
// 429.770 us; speedup vs baseline: 4.2677x; 4.2677x over previous
//
#include <hip/hip_runtime.h>

#define NN 50000
#define EE 800000
#define FIN 128
#define DD 64
#define RR 8
#define LL 3

#define ND (NN*DD)      // 3,200,000
#define NR (NN*RR)      // 400,000

#define SB 1024
#define NSB ((NR + SB - 1) / SB)   // 391
#define ECAP 2048
#define AS 72           // LDS A-tile row stride in shorts (bank-spread)
#define KB 576          // K total per layer GEMM (8 rel + root) * 64

typedef __attribute__((ext_vector_type(8))) short bf16x8;
typedef __attribute__((ext_vector_type(4))) float f32x4;

__device__ __forceinline__ unsigned short f2bf(float x) {
  unsigned u = __float_as_uint(x);
  u += 0x7fff + ((u >> 16) & 1);           // round-to-nearest-even
  return (unsigned short)(u >> 16);
}
__device__ __forceinline__ void split_bf(float x, short& h, short& l) {
  unsigned short hu = f2bf(x);
  float hf = __uint_as_float((unsigned)hu << 16);
  h = (short)hu;
  l = (short)f2bf(x - hf);
}

// ---- precompute bf16 hi/lo transposed weights -------------------------------
// Btp[l][p][n][k] (k: 8*64 rel + 64 root), flat ((l*2+p)*64+n)*KB + k
__global__ void k_prepB(const float* __restrict__ W_rel,
                        const float* __restrict__ W_root,
                        short* __restrict__ Btp) {
  const int idx = blockIdx.x * 256 + threadIdx.x;
  if (idx >= LL * DD * KB) return;
  const int k = idx % KB, n = (idx / KB) % DD, l = idx / (KB * DD);
  float w;
  if (k < 512) w = W_rel[(((size_t)l*RR + (k >> 6))*DD + (k & 63))*DD + n];
  else         w = W_root[((size_t)l*DD + (k - 512))*DD + n];
  short hi, lo; split_bf(w, hi, lo);
  Btp[((size_t)(l*2+0)*DD + n)*KB + k] = hi;
  Btp[((size_t)(l*2+1)*DD + n)*KB + k] = lo;
}
// Wt[p][n][k], flat (p*64+n)*128+k
__global__ void k_prepWin(const float* __restrict__ W_in, short* __restrict__ Wt) {
  const int idx = blockIdx.x * 256 + threadIdx.x;
  if (idx >= DD * FIN) return;
  const int k = idx % FIN, n = idx / FIN;
  float w = W_in[(size_t)k*DD + n];
  short hi, lo; split_bf(w, hi, lo);
  Wt[((size_t)0*DD + n)*FIN + k] = hi;
  Wt[((size_t)1*DD + n)*FIN + k] = lo;
}

// ---- input projection: h = relu(x @ W_in + b_in) via split-bf16 MFMA --------
__global__ __launch_bounds__(256) void k_input_mfma(
    const float* __restrict__ x, const short* __restrict__ Wt,
    const float* __restrict__ b, float* __restrict__ h) {
  __shared__ short Ah[DD * 136];   // 64 rows x K=128, stride 136
  __shared__ short Al[DD * 136];
  const int t = threadIdx.x;
  const int lane = t & 63, wv = t >> 6;
  const int lr = lane & 15, lc = lane >> 4;
  const int n0 = blockIdx.x * 64;

  { // stage x rows as hi/lo bf16
    const int row = t >> 2, cb = (t & 3) * 32;
    const int n = n0 + row;
    #pragma unroll
    for (int i = 0; i < 8; ++i) {
      const int col = cb + i * 4;
      float4 v = make_float4(0.f,0.f,0.f,0.f);
      if (n < NN) v = *(const float4*)(x + (size_t)n*FIN + col);
      short h0,l0,h1,l1,h2,l2,h3,l3;
      split_bf(v.x,h0,l0); split_bf(v.y,h1,l1);
      split_bf(v.z,h2,l2); split_bf(v.w,h3,l3);
      unsigned long long ph = (unsigned short)h0 | ((unsigned long long)(unsigned short)h1<<16)
          | ((unsigned long long)(unsigned short)h2<<32) | ((unsigned long long)(unsigned short)h3<<48);
      unsigned long long pl = (unsigned short)l0 | ((unsigned long long)(unsigned short)l1<<16)
          | ((unsigned long long)(unsigned short)l2<<32) | ((unsigned long long)(unsigned short)l3<<48);
      *(unsigned long long*)&Ah[row*136 + col] = ph;
      *(unsigned long long*)&Al[row*136 + col] = pl;
    }
  }
  __syncthreads();

  const int m0 = wv * 16;
  f32x4 acc[4];
  #pragma unroll
  for (int nt = 0; nt < 4; ++nt) acc[nt] = (f32x4){0.f,0.f,0.f,0.f};
  const int aoff = (m0 + lr)*136 + lc*8;
  int boff[4];
  #pragma unroll
  for (int nt = 0; nt < 4; ++nt) boff[nt] = (nt*16 + lr)*FIN + lc*8;

  #pragma unroll
  for (int ks = 0; ks < 4; ++ks) {
    const bf16x8 ah = *(const bf16x8*)&Ah[aoff + ks*32];
    const bf16x8 al = *(const bf16x8*)&Al[aoff + ks*32];
    #pragma unroll
    for (int nt = 0; nt < 4; ++nt) {
      const bf16x8 bh = *(const bf16x8*)(Wt + boff[nt] + ks*32);
      const bf16x8 bl = *(const bf16x8*)(Wt + DD*FIN + boff[nt] + ks*32);
      acc[nt] = __builtin_amdgcn_mfma_f32_16x16x32_bf16(ah, bh, acc[nt], 0, 0, 0);
      acc[nt] = __builtin_amdgcn_mfma_f32_16x16x32_bf16(al, bh, acc[nt], 0, 0, 0);
      acc[nt] = __builtin_amdgcn_mfma_f32_16x16x32_bf16(ah, bl, acc[nt], 0, 0, 0);
    }
  }
  #pragma unroll
  for (int nt = 0; nt < 4; ++nt) {
    const float bb = b[nt*16 + lr];
    #pragma unroll
    for (int i = 0; i < 4; ++i) {
      const int m = n0 + m0 + lc*4 + i;
      if (m < NN) h[(size_t)m*DD + nt*16 + lr] = fmaxf(acc[nt][i] + bb, 0.f);
    }
  }
}

// ---------------- CSR build keyed by (et * NN + dst) ------------------------
__global__ void k_hist(const int* __restrict__ ei, const float* __restrict__ ea,
                       int* __restrict__ rp) {
  const int e = blockIdx.x * 256 + threadIdx.x;
  if (e >= EE) return;
  atomicAdd(&rp[(int)ea[2*e + 1] * NN + ei[EE + e]], 1);
}

__global__ __launch_bounds__(256) void k_scan1(int* __restrict__ rp,
                                               int* __restrict__ part) {
  __shared__ int ls[256];
  const int t = threadIdx.x;
  const int base = blockIdx.x * SB + t * 4;
  int v[4] = {0,0,0,0};
  #pragma unroll
  for (int i = 0; i < 4; ++i)
    if (base + i < NR) v[i] = rp[base + i];
  const int tsum = v[0] + v[1] + v[2] + v[3];
  ls[t] = tsum; __syncthreads();
  #pragma unroll
  for (int off = 1; off < 256; off <<= 1) {
    int x = (t >= off) ? ls[t - off] : 0;
    __syncthreads();
    ls[t] += x;
    __syncthreads();
  }
  if (t == 255) part[blockIdx.x] = ls[255];
  int run = ls[t] - tsum;
  #pragma unroll
  for (int i = 0; i < 4; ++i) {
    if (base + i < NR) rp[base + i] = run;
    run += v[i];
  }
}

__global__ __launch_bounds__(512) void k_scan2(int* __restrict__ part) {
  __shared__ int ls[512];
  const int t = threadIdx.x;
  const int v = (t < NSB) ? part[t] : 0;
  ls[t] = v; __syncthreads();
  #pragma unroll
  for (int off = 1; off < 512; off <<= 1) {
    int x = (t >= off) ? ls[t - off] : 0;
    __syncthreads();
    ls[t] += x;
    __syncthreads();
  }
  if (t < NSB) part[t] = ls[t] - v;
}

__global__ __launch_bounds__(256) void k_scan3(int* __restrict__ rp,
                                               const int* __restrict__ part,
                                               int* __restrict__ fill) {
  const int base = blockIdx.x * SB + threadIdx.x * 4;
  const int off = part[blockIdx.x];
  #pragma unroll
  for (int i = 0; i < 4; ++i)
    if (base + i < NR) {
      const int r = rp[base + i] + off;
      rp[base + i] = r;
      fill[base + i] = r;
    }
  if (blockIdx.x == 0 && threadIdx.x == 0) rp[NR] = EE;
}

__global__ void k_reorder(const int* __restrict__ ei, const float* __restrict__ ea,
                          int* __restrict__ fill, unsigned short* __restrict__ eidx) {
  const int e = blockIdx.x * 256 + threadIdx.x;
  if (e >= EE) return;
  const int key = (int)ea[2*e + 1] * NN + ei[EE + e];
  const int pos = atomicAdd(&fill[key], 1);
  eidx[pos] = (unsigned short)ei[e];
}

// ---------------- fused per-layer kernel -------------------------------------
// 64 dst nodes / block, 256 threads. Gather produces A-chunk [64m][64k] as
// split-bf16 (hi/lo) in SINGLE-buffered LDS (25 KB -> ~5-6 blocks/CU), with a
// 16-deep software-pipelined load stream per wave. C = sum_kk A_kk @ B_kk via
// 3x MFMA 16x16x32 per fragment pair. B-frags from precomputed transposed
// global table (L2-resident). MFMA overlap across waves/blocks, not in-wave.
__global__ __launch_bounds__(256) void k_layer(
    const float* __restrict__ h, const unsigned short* __restrict__ eidx,
    const int* __restrict__ rp, const short* __restrict__ Btp,
    const float* __restrict__ bias, float* __restrict__ outh) {
  __shared__ short Ah[DD * AS];            //  9,216 B
  __shared__ short Al[DD * AS];            //  9,216 B
  __shared__ unsigned short els[ECAP];     //  4,096 B
  __shared__ int rpls[RR][65];             //  2,080 B
  __shared__ int baseL[RR + 1];

  const int t = threadIdx.x;
  const int lane = t & 63, wv = t >> 6;
  const int lr = lane & 15, lc = lane >> 4;
  const int n0 = blockIdx.x * 64;
  const int j0 = wv * 16;
  const float* hl = h + lane;

  for (int i = t; i < RR * 65; i += 256) {
    const int kk = i / 65, j = i - kk * 65;
    int g = n0 + j; if (g > NN) g = NN;
    rpls[kk][j] = rp[kk * NN + g];
  }
  __syncthreads();
  if (t == 0) {
    int s = 0;
    #pragma unroll
    for (int k = 0; k < RR; ++k) { baseL[k] = s; s += rpls[k][64] - rpls[k][0]; }
    baseL[RR] = s;
  }
  __syncthreads();
  const bool fit = baseL[RR] <= ECAP;
  if (fit) {
    for (int k = 0; k < RR; ++k) {
      const int g0 = rpls[k][0], sp = rpls[k][64] - g0, b0 = baseL[k];
      for (int i = t; i < sp; i += 256) els[b0 + i] = eidx[g0 + i];
    }
  }
  __syncthreads();

  auto gather = [&](int kk) {
    const int ebeg = rpls[kk][j0], eend = rpls[kk][j0 + 16];
    int j = j0;
    int nxt = rpls[kk][j0 + 1];
    float acc = 0.f;
    auto flush = [&]() {
      const int cnt = nxt - rpls[kk][j];
      float m = (cnt > 1) ? acc * (1.0f / (float)cnt) : acc;
      short hb, lb; split_bf(m, hb, lb);
      Ah[j * AS + lane] = hb;
      Al[j * AS + lane] = lb;
    };
    auto proc = [&](float v, int e2) {
      while (e2 >= nxt) { flush(); acc = 0.f; ++j; nxt = rpls[kk][j + 1]; }
      acc += v;
    };
    auto scan = [&](auto srcAt) {
      int e = ebeg;
      for (; e + 15 < eend; e += 16) {   // 16 independent h-row loads in flight
        int s[16]; float v[16];
        #pragma unroll
        for (int i = 0; i < 16; ++i) s[i] = srcAt(e + i);
        #pragma unroll
        for (int i = 0; i < 16; ++i) v[i] = hl[(size_t)s[i] * DD];
        #pragma unroll
        for (int i = 0; i < 16; ++i) proc(v[i], e + i);
      }
      if (e + 7 < eend) {
        int s[8]; float v[8];
        #pragma unroll
        for (int i = 0; i < 8; ++i) s[i] = srcAt(e + i);
        #pragma unroll
        for (int i = 0; i < 8; ++i) v[i] = hl[(size_t)s[i] * DD];
        #pragma unroll
        for (int i = 0; i < 8; ++i) proc(v[i], e + i);
        e += 8;
      }
      for (; e < eend; ++e) proc(hl[(size_t)srcAt(e) * DD], e);
    };
    if (fit) {
      const int lb2 = baseL[kk] - rpls[kk][0];
      scan([&](int e) { return (int)els[lb2 + e]; });
    } else {
      scan([&](int e) { return (int)eidx[e]; });
    }
    while (true) {                       // flush current + remaining nodes
      flush();
      acc = 0.f; ++j;
      if (j >= j0 + 16) break;
      nxt = rpls[kk][j + 1];
    }
  };
  auto root_stage = [&]() {
    for (int jj = 0; jj < 16; jj += 4) {
      float v[4];
      #pragma unroll
      for (int i = 0; i < 4; ++i) {
        const int n = n0 + j0 + jj + i;
        v[i] = (n < NN) ? h[(size_t)n * DD + lane] : 0.f;
      }
      #pragma unroll
      for (int i = 0; i < 4; ++i) {
        short hb, lb; split_bf(v[i], hb, lb);
        Ah[(j0 + jj + i) * AS + lane] = hb;
        Al[(j0 + jj + i) * AS + lane] = lb;
      }
    }
  };

  const int m0 = wv * 16;
  f32x4 acc[4];
  #pragma unroll
  for (int nt = 0; nt < 4; ++nt) acc[nt] = (f32x4){0.f,0.f,0.f,0.f};
  const int aoff = (m0 + lr) * AS + lc * 8;
  int boff[4];
  #pragma unroll
  for (int nt = 0; nt < 4; ++nt) boff[nt] = (nt*16 + lr)*KB + lc*8;
  const short* Blo = Btp + (size_t)DD * KB;

  #pragma unroll 1
  for (int kk = 0; kk < 9; ++kk) {
    if (kk < 8) gather(kk);
    else        root_stage();
    __syncthreads();   // B1: Ah/Al writes visible to all waves
    const int koff = kk * 64;
    #pragma unroll
    for (int ks = 0; ks < 2; ++ks) {
      const bf16x8 ah = *(const bf16x8*)&Ah[aoff + ks*32];
      const bf16x8 al = *(const bf16x8*)&Al[aoff + ks*32];
      #pragma unroll
      for (int nt = 0; nt < 4; ++nt) {
        const bf16x8 bh = *(const bf16x8*)(Btp + boff[nt] + koff + ks*32);
        const bf16x8 bl = *(const bf16x8*)(Blo + boff[nt] + koff + ks*32);
        acc[nt] = __builtin_amdgcn_mfma_f32_16x16x32_bf16(ah, bh, acc[nt], 0, 0, 0);
        acc[nt] = __builtin_amdgcn_mfma_f32_16x16x32_bf16(al, bh, acc[nt], 0, 0, 0);
        acc[nt] = __builtin_amdgcn_mfma_f32_16x16x32_bf16(ah, bl, acc[nt], 0, 0, 0);
      }
    }
    __syncthreads();   // B2: all MFMA LDS reads done before next gather rewrite
  }

  #pragma unroll
  for (int nt = 0; nt < 4; ++nt) {
    const float bb = bias[nt*16 + lr];
    #pragma unroll
    for (int i = 0; i < 4; ++i) {
      const int m = n0 + m0 + lc*4 + i;
      if (m < NN) outh[(size_t)m*DD + nt*16 + lr] = fmaxf(acc[nt][i] + bb, 0.f);
    }
  }
}

__global__ void k_edist(const float* __restrict__ ea, float* __restrict__ out) {
  const int e = blockIdx.x * 256 + threadIdx.x;
  if (e < EE) out[e] = ea[2*e];
}

extern "C" void kernel_launch(void* const* d_in, const int* in_sizes, int n_in,
                              void* d_out, int out_size, void* d_ws, size_t ws_size,
                              hipStream_t stream) {
  const float* x      = (const float*)d_in[0];
  const int*   ei     = (const int*)d_in[1];
  const float* ea     = (const float*)d_in[2];
  const float* W_in   = (const float*)d_in[3];
  const float* b_in   = (const float*)d_in[4];
  const float* W_rel  = (const float*)d_in[5];
  const float* W_root = (const float*)d_in[6];
  const float* b_conv = (const float*)d_in[7];
  float* out = (float*)d_out;

  // ws layout (~30.9 MB)
  char* ws = (char*)d_ws;
  float*          hA   = (float*)(ws);                       // 12,800,000
  float*          hB   = (float*)(ws + 12800000);            // 12,800,000
  int*            rp   = (int*)  (ws + 25600000);            // 1,600,256
  int*            fill = (int*)  (ws + 27200256);            // 1,600,000
  unsigned short* eidx = (unsigned short*)(ws + 28800256);   // 1,600,000
  int*            part = (int*)  (ws + 30400256);            // 2,048
  short*          Btp  = (short*)(ws + 30402304);            // 442,368
  short*          Wt   = (short*)(ws + 30844672);            // 32,768

  k_edist<<<(EE + 255)/256, 256, 0, stream>>>(ea, out + (size_t)ND);
  k_prepB<<<(LL*DD*KB + 255)/256, 256, 0, stream>>>(W_rel, W_root, Btp);
  k_prepWin<<<(DD*FIN + 255)/256, 256, 0, stream>>>(W_in, Wt);
  k_input_mfma<<<(NN + 63)/64, 256, 0, stream>>>(x, Wt, b_in, hA);

  // CSR keyed (et, dst) — built once, reused by all 3 layers
  hipMemsetAsync(rp, 0, (size_t)NR*4, stream);
  k_hist<<<(EE + 255)/256, 256, 0, stream>>>(ei, ea, rp);
  k_scan1<<<NSB, 256, 0, stream>>>(rp, part);
  k_scan2<<<1, 512, 0, stream>>>(part);
  k_scan3<<<NSB, 256, 0, stream>>>(rp, part, fill);
  k_reorder<<<(EE + 255)/256, 256, 0, stream>>>(ei, ea, fill, eidx);

  const int NBL = (NN + 63) / 64;   // 782
  const float* hin = hA;
  for (int l = 0; l < LL; ++l) {
    float* hout = (l == 2) ? out : ((l == 0) ? hB : hA);
    k_layer<<<NBL, 256, 0, stream>>>(hin, eidx, rp,
        Btp + (size_t)l*2*DD*KB, b_conv + (size_t)l*DD, hout);
    hin = hout;
  }
}

// Round 3
// 403.734 us; speedup vs baseline: 4.5429x; 1.0645x over previous
//
#include <hip/hip_runtime.h>

#define NN 50000
#define EE 800000
#define FIN 128
#define DD 64
#define RR 8
#define LL 3

#define ND (NN*DD)      // 3,200,000
#define NR (NN*RR)      // 400,000

#define SB 1024
#define NSB ((NR + SB - 1) / SB)   // 391
#define ECAP 2048
#define AS 72           // LDS A-tile row stride in shorts (bank-spread)
#define KB 576          // K total per layer GEMM (8 rel + root) * 64

typedef __attribute__((ext_vector_type(8))) short bf16x8;
typedef __attribute__((ext_vector_type(4))) float f32x4;

__device__ __forceinline__ unsigned short f2bf(float x) {
  unsigned u = __float_as_uint(x);
  u += 0x7fff + ((u >> 16) & 1);           // round-to-nearest-even
  return (unsigned short)(u >> 16);
}
__device__ __forceinline__ void split_bf(float x, short& h, short& l) {
  unsigned short hu = f2bf(x);
  float hf = __uint_as_float((unsigned)hu << 16);
  h = (short)hu;
  l = (short)f2bf(x - hf);
}

// ---- precompute bf16 hi/lo transposed weights -------------------------------
// Btp[l][p][n][k] (k: 8*64 rel + 64 root), flat ((l*2+p)*64+n)*KB + k
__global__ void k_prepB(const float* __restrict__ W_rel,
                        const float* __restrict__ W_root,
                        short* __restrict__ Btp) {
  const int idx = blockIdx.x * 256 + threadIdx.x;
  if (idx >= LL * DD * KB) return;
  const int k = idx % KB, n = (idx / KB) % DD, l = idx / (KB * DD);
  float w;
  if (k < 512) w = W_rel[(((size_t)l*RR + (k >> 6))*DD + (k & 63))*DD + n];
  else         w = W_root[((size_t)l*DD + (k - 512))*DD + n];
  short hi, lo; split_bf(w, hi, lo);
  Btp[((size_t)(l*2+0)*DD + n)*KB + k] = hi;
  Btp[((size_t)(l*2+1)*DD + n)*KB + k] = lo;
}
// Wt[p][n][k], flat (p*64+n)*128+k
__global__ void k_prepWin(const float* __restrict__ W_in, short* __restrict__ Wt) {
  const int idx = blockIdx.x * 256 + threadIdx.x;
  if (idx >= DD * FIN) return;
  const int k = idx % FIN, n = idx / FIN;
  float w = W_in[(size_t)k*DD + n];
  short hi, lo; split_bf(w, hi, lo);
  Wt[((size_t)0*DD + n)*FIN + k] = hi;
  Wt[((size_t)1*DD + n)*FIN + k] = lo;
}

// ---- input projection: h = relu(x @ W_in + b_in) via split-bf16 MFMA --------
__global__ __launch_bounds__(256) void k_input_mfma(
    const float* __restrict__ x, const short* __restrict__ Wt,
    const float* __restrict__ b, float* __restrict__ h) {
  __shared__ short Ah[DD * 136];   // 64 rows x K=128, stride 136
  __shared__ short Al[DD * 136];
  const int t = threadIdx.x;
  const int lane = t & 63, wv = t >> 6;
  const int lr = lane & 15, lc = lane >> 4;
  const int n0 = blockIdx.x * 64;

  { // stage x rows as hi/lo bf16
    const int row = t >> 2, cb = (t & 3) * 32;
    const int n = n0 + row;
    #pragma unroll
    for (int i = 0; i < 8; ++i) {
      const int col = cb + i * 4;
      float4 v = make_float4(0.f,0.f,0.f,0.f);
      if (n < NN) v = *(const float4*)(x + (size_t)n*FIN + col);
      short h0,l0,h1,l1,h2,l2,h3,l3;
      split_bf(v.x,h0,l0); split_bf(v.y,h1,l1);
      split_bf(v.z,h2,l2); split_bf(v.w,h3,l3);
      unsigned long long ph = (unsigned short)h0 | ((unsigned long long)(unsigned short)h1<<16)
          | ((unsigned long long)(unsigned short)h2<<32) | ((unsigned long long)(unsigned short)h3<<48);
      unsigned long long pl = (unsigned short)l0 | ((unsigned long long)(unsigned short)l1<<16)
          | ((unsigned long long)(unsigned short)l2<<32) | ((unsigned long long)(unsigned short)l3<<48);
      *(unsigned long long*)&Ah[row*136 + col] = ph;
      *(unsigned long long*)&Al[row*136 + col] = pl;
    }
  }
  __syncthreads();

  const int m0 = wv * 16;
  f32x4 acc[4];
  #pragma unroll
  for (int nt = 0; nt < 4; ++nt) acc[nt] = (f32x4){0.f,0.f,0.f,0.f};
  const int aoff = (m0 + lr)*136 + lc*8;
  int boff[4];
  #pragma unroll
  for (int nt = 0; nt < 4; ++nt) boff[nt] = (nt*16 + lr)*FIN + lc*8;

  #pragma unroll
  for (int ks = 0; ks < 4; ++ks) {
    const bf16x8 ah = *(const bf16x8*)&Ah[aoff + ks*32];
    const bf16x8 al = *(const bf16x8*)&Al[aoff + ks*32];
    #pragma unroll
    for (int nt = 0; nt < 4; ++nt) {
      const bf16x8 bh = *(const bf16x8*)(Wt + boff[nt] + ks*32);
      const bf16x8 bl = *(const bf16x8*)(Wt + DD*FIN + boff[nt] + ks*32);
      acc[nt] = __builtin_amdgcn_mfma_f32_16x16x32_bf16(ah, bh, acc[nt], 0, 0, 0);
      acc[nt] = __builtin_amdgcn_mfma_f32_16x16x32_bf16(al, bh, acc[nt], 0, 0, 0);
      acc[nt] = __builtin_amdgcn_mfma_f32_16x16x32_bf16(ah, bl, acc[nt], 0, 0, 0);
    }
  }
  #pragma unroll
  for (int nt = 0; nt < 4; ++nt) {
    const float bb = b[nt*16 + lr];
    #pragma unroll
    for (int i = 0; i < 4; ++i) {
      const int m = n0 + m0 + lc*4 + i;
      if (m < NN) h[(size_t)m*DD + nt*16 + lr] = fmaxf(acc[nt][i] + bb, 0.f);
    }
  }
}

// ---------------- CSR build keyed by (et * NN + dst) ------------------------
__global__ void k_hist(const int* __restrict__ ei, const float* __restrict__ ea,
                       int* __restrict__ rp) {
  const int e = blockIdx.x * 256 + threadIdx.x;
  if (e >= EE) return;
  atomicAdd(&rp[(int)ea[2*e + 1] * NN + ei[EE + e]], 1);
}

__global__ __launch_bounds__(256) void k_scan1(int* __restrict__ rp,
                                               int* __restrict__ part) {
  __shared__ int ls[256];
  const int t = threadIdx.x;
  const int base = blockIdx.x * SB + t * 4;
  int v[4] = {0,0,0,0};
  #pragma unroll
  for (int i = 0; i < 4; ++i)
    if (base + i < NR) v[i] = rp[base + i];
  const int tsum = v[0] + v[1] + v[2] + v[3];
  ls[t] = tsum; __syncthreads();
  #pragma unroll
  for (int off = 1; off < 256; off <<= 1) {
    int x = (t >= off) ? ls[t - off] : 0;
    __syncthreads();
    ls[t] += x;
    __syncthreads();
  }
  if (t == 255) part[blockIdx.x] = ls[255];
  int run = ls[t] - tsum;
  #pragma unroll
  for (int i = 0; i < 4; ++i) {
    if (base + i < NR) rp[base + i] = run;
    run += v[i];
  }
}

__global__ __launch_bounds__(512) void k_scan2(int* __restrict__ part) {
  __shared__ int ls[512];
  const int t = threadIdx.x;
  const int v = (t < NSB) ? part[t] : 0;
  ls[t] = v; __syncthreads();
  #pragma unroll
  for (int off = 1; off < 512; off <<= 1) {
    int x = (t >= off) ? ls[t - off] : 0;
    __syncthreads();
    ls[t] += x;
    __syncthreads();
  }
  if (t < NSB) part[t] = ls[t] - v;
}

__global__ __launch_bounds__(256) void k_scan3(int* __restrict__ rp,
                                               const int* __restrict__ part,
                                               int* __restrict__ fill) {
  const int base = blockIdx.x * SB + threadIdx.x * 4;
  const int off = part[blockIdx.x];
  #pragma unroll
  for (int i = 0; i < 4; ++i)
    if (base + i < NR) {
      const int r = rp[base + i] + off;
      rp[base + i] = r;
      fill[base + i] = r;
    }
  if (blockIdx.x == 0 && threadIdx.x == 0) rp[NR] = EE;
}

__global__ void k_reorder(const int* __restrict__ ei, const float* __restrict__ ea,
                          int* __restrict__ fill, unsigned short* __restrict__ eidx) {
  const int e = blockIdx.x * 256 + threadIdx.x;
  if (e >= EE) return;
  const int key = (int)ea[2*e + 1] * NN + ei[EE + e];
  const int pos = atomicAdd(&fill[key], 1);
  eidx[pos] = (unsigned short)ei[e];
}

// ---------------- fused per-layer kernel -------------------------------------
// 64 dst nodes / block, 256 threads. Wave wv owns output rows [wv*16,wv*16+16):
// it gathers exactly those A-rows AND its MFMA A-fragments read only those
// rows, so the main loop has NO cross-wave hazard -> NO barriers. Each wave
// free-runs through 8 relations + root, keeping its 16-deep load pipeline
// busy continuously; within-wave LDS RAW/WAR is ordered by lgkmcnt.
__global__ __launch_bounds__(256) void k_layer(
    const float* __restrict__ h, const unsigned short* __restrict__ eidx,
    const int* __restrict__ rp, const short* __restrict__ Btp,
    const float* __restrict__ bias, float* __restrict__ outh) {
  __shared__ short Ah[DD * AS];            //  9,216 B
  __shared__ short Al[DD * AS];            //  9,216 B
  __shared__ unsigned short els[ECAP];     //  4,096 B
  __shared__ int rpls[RR][65];             //  2,080 B
  __shared__ int baseL[RR + 1];

  const int t = threadIdx.x;
  const int lane = t & 63, wv = t >> 6;
  const int lr = lane & 15, lc = lane >> 4;
  const int n0 = blockIdx.x * 64;
  const int j0 = wv * 16;
  const float* hl = h + lane;

  for (int i = t; i < RR * 65; i += 256) {
    const int kk = i / 65, j = i - kk * 65;
    int g = n0 + j; if (g > NN) g = NN;
    rpls[kk][j] = rp[kk * NN + g];
  }
  __syncthreads();
  if (t == 0) {
    int s = 0;
    #pragma unroll
    for (int k = 0; k < RR; ++k) { baseL[k] = s; s += rpls[k][64] - rpls[k][0]; }
    baseL[RR] = s;
  }
  __syncthreads();
  const bool fit = baseL[RR] <= ECAP;
  if (fit) {
    for (int k = 0; k < RR; ++k) {
      const int g0 = rpls[k][0], sp = rpls[k][64] - g0, b0 = baseL[k];
      for (int i = t; i < sp; i += 256) els[b0 + i] = eidx[g0 + i];
    }
  }
  __syncthreads();

  auto gather = [&](int kk) {
    const int ebeg = rpls[kk][j0], eend = rpls[kk][j0 + 16];
    int j = j0;
    int nxt = rpls[kk][j0 + 1];
    float acc = 0.f;
    auto flush = [&]() {
      const int cnt = nxt - rpls[kk][j];
      float m = (cnt > 1) ? acc * (1.0f / (float)cnt) : acc;
      short hb, lb; split_bf(m, hb, lb);
      Ah[j * AS + lane] = hb;
      Al[j * AS + lane] = lb;
    };
    auto proc = [&](float v, int e2) {
      while (e2 >= nxt) { flush(); acc = 0.f; ++j; nxt = rpls[kk][j + 1]; }
      acc += v;
    };
    auto scan = [&](auto srcAt) {
      int e = ebeg;
      for (; e + 15 < eend; e += 16) {   // 16 independent h-row loads in flight
        int s[16]; float v[16];
        #pragma unroll
        for (int i = 0; i < 16; ++i) s[i] = srcAt(e + i);
        #pragma unroll
        for (int i = 0; i < 16; ++i) v[i] = hl[(size_t)s[i] * DD];
        #pragma unroll
        for (int i = 0; i < 16; ++i) proc(v[i], e + i);
      }
      if (e + 7 < eend) {
        int s[8]; float v[8];
        #pragma unroll
        for (int i = 0; i < 8; ++i) s[i] = srcAt(e + i);
        #pragma unroll
        for (int i = 0; i < 8; ++i) v[i] = hl[(size_t)s[i] * DD];
        #pragma unroll
        for (int i = 0; i < 8; ++i) proc(v[i], e + i);
        e += 8;
      }
      for (; e < eend; ++e) proc(hl[(size_t)srcAt(e) * DD], e);
    };
    if (fit) {
      const int lb2 = baseL[kk] - rpls[kk][0];
      scan([&](int e) { return (int)els[lb2 + e]; });
    } else {
      scan([&](int e) { return (int)eidx[e]; });
    }
    while (true) {                       // flush current + remaining nodes
      flush();
      acc = 0.f; ++j;
      if (j >= j0 + 16) break;
      nxt = rpls[kk][j + 1];
    }
  };
  auto root_stage = [&]() {
    for (int jj = 0; jj < 16; jj += 4) {
      float v[4];
      #pragma unroll
      for (int i = 0; i < 4; ++i) {
        const int n = n0 + j0 + jj + i;
        v[i] = (n < NN) ? h[(size_t)n * DD + lane] : 0.f;
      }
      #pragma unroll
      for (int i = 0; i < 4; ++i) {
        short hb, lb; split_bf(v[i], hb, lb);
        Ah[(j0 + jj + i) * AS + lane] = hb;
        Al[(j0 + jj + i) * AS + lane] = lb;
      }
    }
  };

  const int m0 = wv * 16;
  f32x4 acc[4];
  #pragma unroll
  for (int nt = 0; nt < 4; ++nt) acc[nt] = (f32x4){0.f,0.f,0.f,0.f};
  const int aoff = (m0 + lr) * AS + lc * 8;
  int boff[4];
  #pragma unroll
  for (int nt = 0; nt < 4; ++nt) boff[nt] = (nt*16 + lr)*KB + lc*8;
  const short* Blo = Btp + (size_t)DD * KB;

  #pragma unroll 1
  for (int kk = 0; kk < 9; ++kk) {
    if (kk < 8) gather(kk);
    else        root_stage();
    // no barrier: wave consumes only its own 16 LDS rows (lgkmcnt orders
    // the flush ds_writes before the fragment ds_reads within the wave)
    const int koff = kk * 64;
    #pragma unroll
    for (int ks = 0; ks < 2; ++ks) {
      const bf16x8 ah = *(const bf16x8*)&Ah[aoff + ks*32];
      const bf16x8 al = *(const bf16x8*)&Al[aoff + ks*32];
      #pragma unroll
      for (int nt = 0; nt < 4; ++nt) {
        const bf16x8 bh = *(const bf16x8*)(Btp + boff[nt] + koff + ks*32);
        const bf16x8 bl = *(const bf16x8*)(Blo + boff[nt] + koff + ks*32);
        acc[nt] = __builtin_amdgcn_mfma_f32_16x16x32_bf16(ah, bh, acc[nt], 0, 0, 0);
        acc[nt] = __builtin_amdgcn_mfma_f32_16x16x32_bf16(al, bh, acc[nt], 0, 0, 0);
        acc[nt] = __builtin_amdgcn_mfma_f32_16x16x32_bf16(ah, bl, acc[nt], 0, 0, 0);
      }
    }
    // no barrier: next gather rewrites only this wave's rows
  }

  #pragma unroll
  for (int nt = 0; nt < 4; ++nt) {
    const float bb = bias[nt*16 + lr];
    #pragma unroll
    for (int i = 0; i < 4; ++i) {
      const int m = n0 + m0 + lc*4 + i;
      if (m < NN) outh[(size_t)m*DD + nt*16 + lr] = fmaxf(acc[nt][i] + bb, 0.f);
    }
  }
}

__global__ void k_edist(const float* __restrict__ ea, float* __restrict__ out) {
  const int e = blockIdx.x * 256 + threadIdx.x;
  if (e < EE) out[e] = ea[2*e];
}

extern "C" void kernel_launch(void* const* d_in, const int* in_sizes, int n_in,
                              void* d_out, int out_size, void* d_ws, size_t ws_size,
                              hipStream_t stream) {
  const float* x      = (const float*)d_in[0];
  const int*   ei     = (const int*)d_in[1];
  const float* ea     = (const float*)d_in[2];
  const float* W_in   = (const float*)d_in[3];
  const float* b_in   = (const float*)d_in[4];
  const float* W_rel  = (const float*)d_in[5];
  const float* W_root = (const float*)d_in[6];
  const float* b_conv = (const float*)d_in[7];
  float* out = (float*)d_out;

  // ws layout (~30.9 MB)
  char* ws = (char*)d_ws;
  float*          hA   = (float*)(ws);                       // 12,800,000
  float*          hB   = (float*)(ws + 12800000);            // 12,800,000
  int*            rp   = (int*)  (ws + 25600000);            // 1,600,256
  int*            fill = (int*)  (ws + 27200256);            // 1,600,000
  unsigned short* eidx = (unsigned short*)(ws + 28800256);   // 1,600,000
  int*            part = (int*)  (ws + 30400256);            // 2,048
  short*          Btp  = (short*)(ws + 30402304);            // 442,368
  short*          Wt   = (short*)(ws + 30844672);            // 32,768

  k_edist<<<(EE + 255)/256, 256, 0, stream>>>(ea, out + (size_t)ND);
  k_prepB<<<(LL*DD*KB + 255)/256, 256, 0, stream>>>(W_rel, W_root, Btp);
  k_prepWin<<<(DD*FIN + 255)/256, 256, 0, stream>>>(W_in, Wt);
  k_input_mfma<<<(NN + 63)/64, 256, 0, stream>>>(x, Wt, b_in, hA);

  // CSR keyed (et, dst) — built once, reused by all 3 layers
  hipMemsetAsync(rp, 0, (size_t)NR*4, stream);
  k_hist<<<(EE + 255)/256, 256, 0, stream>>>(ei, ea, rp);
  k_scan1<<<NSB, 256, 0, stream>>>(rp, part);
  k_scan2<<<1, 512, 0, stream>>>(part);
  k_scan3<<<NSB, 256, 0, stream>>>(rp, part, fill);
  k_reorder<<<(EE + 255)/256, 256, 0, stream>>>(ei, ea, fill, eidx);

  const int NBL = (NN + 63) / 64;   // 782
  const float* hin = hA;
  for (int l = 0; l < LL; ++l) {
    float* hout = (l == 2) ? out : ((l == 0) ? hB : hA);
    k_layer<<<NBL, 256, 0, stream>>>(hin, eidx, rp,
        Btp + (size_t)l*2*DD*KB, b_conv + (size_t)l*DD, hout);
    hin = hout;
  }
}